// Round 3
// baseline (389.102 us; speedup 1.0000x reference)
//
#include <hip/hip_runtime.h>

// StyleAttentionExtractor: B=16, C=512, H=W=64 (HW=4096), S=19, seg 256x256.
// out[b,s,:] = where(cnt>0, relu(maskedmean(x)) @ Ws[s]^T + bs[s], 0)

#define NB 16
#define NS 19
#define NC 512
#define NHW 4096

// ---------------- K1: build 19-bit mask word per (b,hw) + count partials ----
// nearest resize 256->64: src index = 4*dst (floor(i*256/64) = 4i).
// 1024 blocks x 64 threads: block = (b, h-row); lanes cover w. 19 loads in flight.
__global__ __launch_bounds__(64) void k1_mask(const float* __restrict__ seg,
                                              unsigned int* __restrict__ bm,
                                              unsigned int* __restrict__ cnt_part) {
  int l = threadIdx.x;             // w (0..63)
  int bid = blockIdx.x;            // 1024 = b(16) * h(64)
  int b = bid >> 6, h = bid & 63;
  const float* p = seg + (size_t)b * NS * 65536 + (size_t)(h << 2) * 256 + (l << 2);
  unsigned int bits = 0u;
#pragma unroll
  for (int s = 0; s < NS; ++s) {
    float v = p[(size_t)s * 65536];
    if (v != 0.0f) bits |= (1u << s);
  }
  bm[(b << 12) + (h << 6) + l] = bits;
#pragma unroll
  for (int s = 0; s < NS; ++s) {
    unsigned long long bal = __ballot((bits >> s) & 1u);
    if (l == 0) cnt_part[(size_t)((b << 6) + h) * NS + s] = (unsigned int)__popcll(bal);
  }
}

// ---------------- K2: masked segment sums, streaming pass over x ------------
// Grid 2048 = b(16) x cg(32) x quarter(4). Wave owns (b, 4 channels, 1024 hw).
// All 20 loads (16 x-float4 + 4 bm-uint4) issued before the fmac chain -> MLP.
__global__ __launch_bounds__(256) void k2_sums(const float* __restrict__ x,
                                               const unsigned int* __restrict__ bm,
                                               float* __restrict__ sums) {
  int bid = blockIdx.x;
  int b = bid >> 7;
  int cgidx = (bid >> 2) & 31;
  int q = bid & 3;
  int wave = threadIdx.x >> 6, lane = threadIdx.x & 63;
  int cg = (cgidx << 2) + wave;    // 0..127 channel-group of 4
  int ch0 = cg << 2;
  const float4* px0 = (const float4*)(x + ((size_t)(b * NC + ch0 + 0) << 12));
  const float4* px1 = (const float4*)(x + ((size_t)(b * NC + ch0 + 1) << 12));
  const float4* px2 = (const float4*)(x + ((size_t)(b * NC + ch0 + 2) << 12));
  const float4* px3 = (const float4*)(x + ((size_t)(b * NC + ch0 + 3) << 12));
  const uint4* pbm = (const uint4*)(bm + ((size_t)b << 12));
  int base = (q << 8) + lane;      // float4 units; quarter = 256 float4 = 1024 hw

  // issue everything up front
  float4 xv0[4], xv1[4], xv2[4], xv3[4];
  uint4 mv[4];
#pragma unroll
  for (int it = 0; it < 4; ++it) {
    int idx = base + (it << 6);
    xv0[it] = px0[idx];
    xv1[it] = px1[idx];
    xv2[it] = px2[idx];
    xv3[it] = px3[idx];
    mv[it] = pbm[idx];
  }

  float acc[4][NS];
#pragma unroll
  for (int ci = 0; ci < 4; ++ci)
#pragma unroll
    for (int s = 0; s < NS; ++s) acc[ci][s] = 0.0f;

#pragma unroll
  for (int it = 0; it < 4; ++it) {
#pragma unroll
    for (int s = 0; s < NS; ++s) {
      float m0 = (float)((mv[it].x >> s) & 1u);
      float m1 = (float)((mv[it].y >> s) & 1u);
      float m2 = (float)((mv[it].z >> s) & 1u);
      float m3 = (float)((mv[it].w >> s) & 1u);
      acc[0][s] += xv0[it].x * m0; acc[0][s] += xv0[it].y * m1; acc[0][s] += xv0[it].z * m2; acc[0][s] += xv0[it].w * m3;
      acc[1][s] += xv1[it].x * m0; acc[1][s] += xv1[it].y * m1; acc[1][s] += xv1[it].z * m2; acc[1][s] += xv1[it].w * m3;
      acc[2][s] += xv2[it].x * m0; acc[2][s] += xv2[it].y * m1; acc[2][s] += xv2[it].z * m2; acc[2][s] += xv2[it].w * m3;
      acc[3][s] += xv3[it].x * m0; acc[3][s] += xv3[it].y * m1; acc[3][s] += xv3[it].z * m2; acc[3][s] += xv3[it].w * m3;
    }
  }

  // cross-lane reduction + store partials: sums[q][b][s][c]
  float* sp = sums + (((size_t)q * NB + b) * NS) * (size_t)NC + ch0;
#pragma unroll
  for (int ci = 0; ci < 4; ++ci) {
#pragma unroll
    for (int s = 0; s < NS; ++s) {
      float v = acc[ci][s];
#pragma unroll
      for (int off = 32; off > 0; off >>= 1) v += __shfl_xor(v, off, 64);
      if (lane == 0) sp[(size_t)s * NC + ci] = v;
    }
  }
}

// ---------------- K3a: counts -> feat = relu(mean), zero-mask ---------------
// Block per (b,s). Writes feat[s][b][ci] + mask[s][b].
__global__ __launch_bounds__(256) void k3a_feat(const float* __restrict__ sums,
                                                const unsigned int* __restrict__ cnt_part,
                                                float* __restrict__ featbuf,
                                                float* __restrict__ maskv) {
  int bid = blockIdx.x;  // 304 = B*S
  int b = bid / NS, s = bid - b * NS;
  int t = threadIdx.x, lane = t & 63;

  unsigned int cp = cnt_part[(size_t)((b << 6) + lane) * NS + s];
#pragma unroll
  for (int off = 32; off > 0; off >>= 1) cp += __shfl_xor(cp, off, 64);

  float* f = featbuf + ((size_t)s * NB + b) * NC;
  if (cp == 0u) {
    ((float2*)f)[t] = make_float2(0.0f, 0.0f);
    if (t == 0) maskv[s * NB + b] = 0.0f;
    return;
  }
  if (t == 0) maskv[s * NB + b] = 1.0f;
  float inv = 1.0f / (float)cp;
  const float* q0 = sums + (((size_t)0 * NB + b) * NS + s) * NC;
  const float* q1 = sums + (((size_t)1 * NB + b) * NS + s) * NC;
  const float* q2 = sums + (((size_t)2 * NB + b) * NS + s) * NC;
  const float* q3 = sums + (((size_t)3 * NB + b) * NS + s) * NC;
#pragma unroll
  for (int k = 0; k < 2; ++k) {
    int i = t + (k << 8);
    float v = (q0[i] + q1[i] + q2[i] + q3[i]) * inv;
    f[i] = v > 0.0f ? v : 0.0f;
  }
}

// ---------------- K3b: per-segment linear, Ws read exactly once -------------
// Grid 19*64 blocks; block stages feat[s] (16x512 = 32 KB) in LDS and owns a
// cotile of 8 c_out rows (2 per wave): Ws rows coalesced, read exactly once.
__global__ __launch_bounds__(256) void k3b_lin(const float* __restrict__ featbuf,
                                               const float* __restrict__ maskv,
                                               const float* __restrict__ Ws,
                                               const float* __restrict__ bsv,
                                               float* __restrict__ out) {
  __shared__ __align__(16) float feat[NB * NC];  // 32 KB
  int bid = blockIdx.x;          // 1216 = s(19) * cotile(64)
  int s = bid >> 6;
  int cot = (bid & 63) << 3;
  int t = threadIdx.x, lane = t & 63, wave = t >> 6;
  int coA = cot + wave, coB = cot + wave + 4;

  // issue Ws row loads first (read-once from HBM, longest latency)
  const float4* wrA = (const float4*)(Ws + ((size_t)s * NC + coA) * NC);
  const float4* wrB = (const float4*)(Ws + ((size_t)s * NC + coB) * NC);
  float4 wA0 = wrA[lane], wA1 = wrA[64 + lane];
  float4 wB0 = wrB[lane], wB1 = wrB[64 + lane];
  float biasA = bsv[s * NC + coA], biasB = bsv[s * NC + coB];

  // cooperative stage of feat[s]: 8192 floats = 2048 float4
  const float4* fsrc = (const float4*)(featbuf + (size_t)s * NB * NC);
  float4* fdst = (float4*)feat;
#pragma unroll
  for (int k = 0; k < 8; ++k) fdst[t + (k << 8)] = fsrc[t + (k << 8)];
  __syncthreads();

  const float4* fv = (const float4*)feat;
  float accA[NB], accB[NB];
#pragma unroll
  for (int b = 0; b < NB; ++b) {
    float4 f0 = fv[(b << 7) + lane];
    float4 f1 = fv[(b << 7) + 64 + lane];
    accA[b] = wA0.x * f0.x + wA0.y * f0.y + wA0.z * f0.z + wA0.w * f0.w +
              wA1.x * f1.x + wA1.y * f1.y + wA1.z * f1.z + wA1.w * f1.w;
    accB[b] = wB0.x * f0.x + wB0.y * f0.y + wB0.z * f0.z + wB0.w * f0.w +
              wB1.x * f1.x + wB1.y * f1.y + wB1.z * f1.z + wB1.w * f1.w;
  }
#pragma unroll
  for (int b = 0; b < NB; ++b) {
    float a = accA[b], c = accB[b];
#pragma unroll
    for (int off = 32; off > 0; off >>= 1) { a += __shfl_xor(a, off, 64); c += __shfl_xor(c, off, 64); }
    if (lane == 0) {
      float m = maskv[s * NB + b];
      out[((size_t)(b * NS + s)) * NC + coA] = (a + biasA) * m;
      out[((size_t)(b * NS + s)) * NC + coB] = (c + biasB) * m;
    }
  }
}

extern "C" void kernel_launch(void* const* d_in, const int* in_sizes, int n_in,
                              void* d_out, int out_size, void* d_ws, size_t ws_size,
                              hipStream_t stream) {
  const float* x   = (const float*)d_in[0];   // [16,512,64,64]
  const float* seg = (const float*)d_in[1];   // [16,19,256,256]
  const float* Ws  = (const float*)d_in[2];   // [19,512,512]
  const float* bsv = (const float*)d_in[3];   // [19,512]
  float* out = (float*)d_out;                 // [16,19,512]

  char* ws = (char*)d_ws;
  size_t off = 0;
  unsigned int* bm       = (unsigned int*)(ws + off); off += 262144;        // 16*4096*4
  unsigned int* cnt_part = (unsigned int*)(ws + off); off += 77824;         // 16*64*19*4
  float*        sums     = (float*)(ws + off);        off += 2490368;       // 4*16*19*512*4
  float*        featbuf  = (float*)(ws + off);        off += 622592;        // 19*16*512*4
  float*        maskv    = (float*)(ws + off);        off += 1216;          // 19*16*4
  // total ws use: ~3.45 MB

  k1_mask<<<1024, 64, 0, stream>>>(seg, bm, cnt_part);
  k2_sums<<<2048, 256, 0, stream>>>(x, bm, sums);
  k3a_feat<<<NB * NS, 256, 0, stream>>>(sums, cnt_part, featbuf, maskv);
  k3b_lin<<<NS * 64, 256, 0, stream>>>(featbuf, maskv, Ws, bsv, out);
}